// Round 5
// baseline (240.901 us; speedup 1.0000x reference)
//
#include <hip/hip_runtime.h>

// StateDependentConv2D: B=8, C=16, H=W=256, K=3 (KK=9), HID=64
//
// Round-5: single fused kernel again (serial temb_kernel removed), grid 2048,
// packed-fp32 epilogue, deeper prefetch pipelines.
//  - MFMA math identical to R4 (harness-verified fragment layouts):
//    s[l,i,pix] = sum_k A[l,i,k]*prev[k,pix] + b1[l,i] via one
//    mfma_f32_16x16x32_bf16 per tap; b1 folded at k=16 with B=1.0.
//  - t-MLP recomputed per block (LDS + 3 barriers, once; ~8 runs/CU total).
//  - 4-row blocks -> grid 2048 (was 1024): lifts the 4-blocks/CU dispatch cap.
//  - Epilogue on the f4 accumulator with elementwise ops -> v_pk_fma_f32;
//    s^4/48 Taylor term dropped (|s|<=0.04 -> out err <1e-6 << tol 7.8e-3).
//  - x window: distance-2 rolling prefetch across taps AND across rows
//    (taps 0/1 of row j+1 issued during row j). prev: full-row-early prefetch.
//    MFMA issued distance-1 ahead of its dependent silu epilogue.
#define BATCH 8
#define CH    16
#define HH    256
#define WW    256
#define CST   (HH * WW)
#define KK    9
#define HID   64

typedef float f4 __attribute__((ext_vector_type(4)));
typedef short s8v __attribute__((ext_vector_type(8)));
typedef __bf16 b8v __attribute__((ext_vector_type(8)));

static __device__ __forceinline__ unsigned short bf16rne(float f) {
    unsigned u = __float_as_uint(f);
    return (unsigned short)((u + 0x7FFFu + ((u >> 16) & 1u)) >> 16);
}
static __device__ __forceinline__ f4 splat4(float v) { f4 r = {v, v, v, v}; return r; }
static __device__ __forceinline__ f4 fma4(f4 a, f4 b, f4 c) { return __builtin_elementwise_fma(a, b, c); }

__global__ __launch_bounds__(256, 4) void sdconv_mfma(
    const float* __restrict__ x,
    const float* __restrict__ prev,
    const float* __restrict__ A,    /* [CH][KK][CH] fp32 */
    const float* __restrict__ b1,   /* [CH][KK] */
    const float* __restrict__ b2,   /* [CH][KK] */
    const float* __restrict__ t_in,
    const float* __restrict__ W1, const float* __restrict__ bm1,
    const float* __restrict__ W2, const float* __restrict__ bm2,
    const float* __restrict__ W3, const float* __restrict__ bm3,
    float* __restrict__ out)
{
    __shared__ float h1s[HID], h2s[HID], tbs[KK];
    const int t   = threadIdx.x;
    const int bid = blockIdx.x;
    const int b   = bid >> 8;        // 256 blocks per batch
    const int blk = bid & 255;       // 64 row-groups x 4 col-groups

    // ---- fused time-embedding MLP: t -> 64 -> 64 -> 9 (exact silu) ----
    if (t < HID) {
        float v = fmaf(t_in[b], W1[t], bm1[t]);
        h1s[t] = v / (1.0f + __expf(-v));
    }
    __syncthreads();
    if (t < HID) {
        float s = bm2[t];
#pragma unroll 16
        for (int k = 0; k < HID; ++k) s = fmaf(h1s[k], W2[k * HID + t], s);
        h2s[t] = s / (1.0f + __expf(-s));
    }
    __syncthreads();
    if (t < KK) {
        float o = bm3[t];
#pragma unroll 16
        for (int k = 0; k < HID; ++k) o = fmaf(h2s[k], W3[k * KK + t], o);
        tbs[t] = o;
    }
    __syncthreads();
    float tb[KK];
#pragma unroll
    for (int i = 0; i < KK; ++i)
        tb[i] = __int_as_float(__builtin_amdgcn_readfirstlane(__float_as_int(tbs[i])));

    // ---- geometry ----
    const int q  = t & 15;           // pixel col in tile / A row
    const int g  = (t >> 4) & 3;     // k-group (operands) / l-group (C/D)
    const int wv = t >> 6;           // wave 0..3
    const int h0 = (blk >> 2) << 2;                 // 4-row span
    const int w0 = ((blk & 3) << 6) + (wv << 4);    // 16-col tile

    const int TL[8] = {0, 1, 2, 3, 5, 6, 7, 8};     // center tap 4 masked

    // ---- A fragments (8 taps), loaded ONCE; b1 folded at k=16 (R4-verified) ----
    s8v afr[8];
#pragma unroll
    for (int ti = 0; ti < 8; ++ti) {
        s8v a = {0, 0, 0, 0, 0, 0, 0, 0};
        if (g < 2) {
            const float* ap = A + (q * KK + TL[ti]) * CH + g * 8;
            f4 a0 = *(const f4*)ap;
            f4 a1 = *(const f4*)(ap + 4);
            a[0] = (short)bf16rne(a0.x); a[1] = (short)bf16rne(a0.y);
            a[2] = (short)bf16rne(a0.z); a[3] = (short)bf16rne(a0.w);
            a[4] = (short)bf16rne(a1.x); a[5] = (short)bf16rne(a1.y);
            a[6] = (short)bf16rne(a1.z); a[7] = (short)bf16rne(a1.w);
        } else if (g == 2) {
            a[0] = (short)bf16rne(b1[q * KK + TL[ti]]);
        }
        afr[ti] = a;
    }

    // ---- c2 = b2 + t_emb per (tap, r) as f4 (matches acc component layout) ----
    int xci[4];
    f4 c2q[8];
#pragma unroll
    for (int r = 0; r < 4; ++r) {
        const int l = 4 * g + r;
        xci[r] = (b * CH + l) * CST;
#pragma unroll
        for (int ti = 0; ti < 8; ++ti)
            c2q[ti][r] = b2[l * KK + TL[ti]] + tb[TL[ti]];
    }

    const int wc = w0 + q;
    const int wcol[3] = { (wc - 1) & (WW - 1), wc, (wc + 1) & (WW - 1) };

    const float* pvb = prev + (size_t)(b * CH + g * 8) * CST;   // deref'd only if g<2

    s8v bs_const = {0, 0, 0, 0, 0, 0, 0, 0};
    if (g == 2) bs_const[0] = (short)0x3F80;    // bf16 1.0 at k=16

    // ---- prev prefetch for j=0 ----
    float pp[8];
    if (g < 2) {
        const float* p0 = pvb + h0 * WW + wc;
#pragma unroll
        for (int e = 0; e < 8; ++e) pp[e] = p0[(size_t)e * CST];
    }

    const float* xp0 = x + xci[0];
    const float* xp1 = x + xci[1];
    const float* xp2 = x + xci[2];
    const float* xp3 = x + xci[3];

    // ---- x pipeline prologue: row j=0, taps 0 (r-1,c-1) and 1 (r-1,c) ----
    const int sr0m = ((h0 - 1) & (HH - 1)) * WW;
    f4 xa, xb, xc;
    { const int o0 = sr0m + wcol[0]; xa.x = xp0[o0]; xa.y = xp1[o0]; xa.z = xp2[o0]; xa.w = xp3[o0]; }
    { const int o1 = sr0m + wcol[1]; xb.x = xp0[o1]; xb.y = xp1[o1]; xb.z = xp2[o1]; xb.w = xp3[o1]; }

#pragma unroll
    for (int j = 0; j < 4; ++j) {
        const int h  = h0 + j;
        const int sr[3]  = { ((h - 1) & (HH - 1)) * WW, h * WW, ((h + 1) & (HH - 1)) * WW };
        const int hn = h0 + ((j + 1) & 3);   // wraps on last j (harmless reload)
        const int srn[3] = { ((hn - 1) & (HH - 1)) * WW, hn * WW, ((hn + 1) & (HH - 1)) * WW };

        // ---- B fragment from prefetched prev (loads issued a full row ago) ----
        s8v bs = bs_const;
        if (g < 2) {
#pragma unroll
            for (int e = 0; e < 8; ++e) bs[e] = (short)bf16rne(pp[e]);
        }
        // prefetch prev for next row
        if (g < 2) {
            const float* pn = pvb + hn * WW + wc;
#pragma unroll
            for (int e = 0; e < 8; ++e) pp[e] = pn[(size_t)e * CST];
        }

        f4 o4 = splat4(0.0f);

        // MFMA pipelined distance-1 ahead of its dependent epilogue
        f4 accA = {0.f, 0.f, 0.f, 0.f};
        accA = __builtin_amdgcn_mfma_f32_16x16x32_bf16(
            __builtin_bit_cast(b8v, afr[0]), __builtin_bit_cast(b8v, bs), accA, 0, 0, 0);

#pragma unroll
        for (int ti = 0; ti < 8; ++ti) {
            // x load at distance-2: taps ti+2 of this row, or taps 0/1 of next row
            int loff;
            if (ti < 6) { const int lt = TL[ti + 2]; loff = sr[lt / 3]  + wcol[lt % 3]; }
            else        { const int lt = TL[ti - 6]; loff = srn[lt / 3] + wcol[lt % 3]; }
            xc.x = xp0[loff]; xc.y = xp1[loff]; xc.z = xp2[loff]; xc.w = xp3[loff];

            f4 accB = {0.f, 0.f, 0.f, 0.f};
            if (ti < 7)
                accB = __builtin_amdgcn_mfma_f32_16x16x32_bf16(
                    __builtin_bit_cast(b8v, afr[ti + 1]), __builtin_bit_cast(b8v, bs), accB, 0, 0, 0);

            // silu Taylor (s^4 dropped: |s|<=0.04 -> err <6e-8) + c2 + conv, packed f32
            const f4 s2 = accA * accA;
            f4 kx = fma4(accA, splat4(0.5f), c2q[ti]);
            kx = fma4(s2, splat4(0.25f), kx);
            o4 = fma4(kx, xa, o4);

            accA = accB;
            xa = xb; xb = xc;
        }

        const int so = h * WW + wc;
        out[xci[0] + so] = o4.x;
        out[xci[1] + so] = o4.y;
        out[xci[2] + so] = o4.z;
        out[xci[3] + so] = o4.w;
    }
}

extern "C" void kernel_launch(void* const* d_in, const int* in_sizes, int n_in,
                              void* d_out, int out_size, void* d_ws, size_t ws_size,
                              hipStream_t stream)
{
    // 0:x 1:t 2:prev_output 3:A 4:b1 5:b2 6:W1 7:bm1 8:W2 9:bm2 10:W3 11:bm3
    const float* x    = (const float*)d_in[0];
    const float* t    = (const float*)d_in[1];
    const float* prev = (const float*)d_in[2];
    const float* A    = (const float*)d_in[3];
    const float* b1   = (const float*)d_in[4];
    const float* b2   = (const float*)d_in[5];
    const float* W1   = (const float*)d_in[6];
    const float* bm1  = (const float*)d_in[7];
    const float* W2   = (const float*)d_in[8];
    const float* bm2  = (const float*)d_in[9];
    const float* W3   = (const float*)d_in[10];
    const float* bm3  = (const float*)d_in[11];
    float* out = (float*)d_out;

    sdconv_mfma<<<BATCH * 256, 256, 0, stream>>>(
        x, prev, A, b1, b2, t, W1, bm1, W2, bm2, W3, bm3, out);
}

// Round 6
// 152.847 us; speedup vs baseline: 1.5761x; 1.5761x over previous
//
#include <hip/hip_runtime.h>

// StateDependentConv2D: B=8, C=16, H=W=256, K=3 (KK=9), HID=64
//
// Round-6: R4's proven MFMA loop body + three safe additions.
//  R5 post-mortem: full unroll of the 4-row loop + cross-row pipeline spilled
//  pipeline state to scratch (WRITE_SIZE 34->160MB, VALUBusy 8.7%). Reverted.
//  Kept from R4 (verified): s[l,i,pix] = sum_k A[l,i,k]*prev[k,pix] + b1 via
//  one mfma_f32_16x16x32_bf16 per tap, A-fragments resident (loaded once),
//  b1 folded at k=16 with B=1.0, distance-1 x prefetch inside the row.
//  Added: (1) t-MLP fused in-block (serial setup kernel cost ~100us/iter),
//  (2) 4-row blocks -> grid 2048 (lifts 4-block/CU dispatch cap),
//  (3) packed-f4 epilogue on the accumulator (v_pk_fma_f32), s^4 Taylor term
//  dropped (|s|<=0.04 -> err <1e-7 << tol 7.8e-3), (4) one-row-ahead prev
//  prefetch (8 VGPRs). j-loop is unroll-1 to keep live state ~110 VGPR.
#define BATCH 8
#define CH    16
#define HH    256
#define WW    256
#define CST   (HH * WW)
#define KK    9
#define HID   64

typedef float f4 __attribute__((ext_vector_type(4)));
typedef short s8v __attribute__((ext_vector_type(8)));
typedef __bf16 b8v __attribute__((ext_vector_type(8)));

static __device__ __forceinline__ unsigned short bf16rne(float f) {
    unsigned u = __float_as_uint(f);
    return (unsigned short)((u + 0x7FFFu + ((u >> 16) & 1u)) >> 16);
}
static __device__ __forceinline__ f4 splat4(float v) { f4 r = {v, v, v, v}; return r; }
static __device__ __forceinline__ f4 fma4(f4 a, f4 b, f4 c) { return __builtin_elementwise_fma(a, b, c); }

__global__ __launch_bounds__(256, 4) void sdconv_mfma(
    const float* __restrict__ x,
    const float* __restrict__ prev,
    const float* __restrict__ A,    /* [CH][KK][CH] fp32 */
    const float* __restrict__ b1,   /* [CH][KK] */
    const float* __restrict__ b2,   /* [CH][KK] */
    const float* __restrict__ t_in,
    const float* __restrict__ W1, const float* __restrict__ bm1,
    const float* __restrict__ W2, const float* __restrict__ bm2,
    const float* __restrict__ W3, const float* __restrict__ bm3,
    float* __restrict__ out)
{
    __shared__ float h1s[HID], h2s[HID], tbs[KK];
    const int t   = threadIdx.x;
    const int bid = blockIdx.x;
    const int b   = bid >> 8;        // 256 blocks per batch
    const int blk = bid & 255;       // 64 row-groups x 4 col-groups

    // ---- fused time-embedding MLP: t -> 64 -> 64 -> 9 (exact silu) ----
    if (t < HID) {
        float v = fmaf(t_in[b], W1[t], bm1[t]);
        h1s[t] = v / (1.0f + __expf(-v));
    }
    __syncthreads();
    if (t < HID) {
        float s = bm2[t];
#pragma unroll 16
        for (int k = 0; k < HID; ++k) s = fmaf(h1s[k], W2[k * HID + t], s);
        h2s[t] = s / (1.0f + __expf(-s));
    }
    __syncthreads();
    if (t < KK) {
        float o = bm3[t];
#pragma unroll 16
        for (int k = 0; k < HID; ++k) o = fmaf(h2s[k], W3[k * KK + t], o);
        tbs[t] = o;
    }
    __syncthreads();
    float tb[KK];
#pragma unroll
    for (int i = 0; i < KK; ++i)
        tb[i] = __int_as_float(__builtin_amdgcn_readfirstlane(__float_as_int(tbs[i])));

    // ---- geometry ----
    const int q  = t & 15;           // pixel col in tile / A row
    const int g  = (t >> 4) & 3;     // k-group (operands) / l-group (C/D)
    const int wv = t >> 6;           // wave 0..3
    const int h0 = (blk >> 2) << 2;                 // 4-row span
    const int w0 = ((blk & 3) << 6) + (wv << 4);    // 16-col tile

    const int TL[8] = {0, 1, 2, 3, 5, 6, 7, 8};     // center tap 4 masked

    // ---- A fragments (8 taps), loaded ONCE; b1 folded at k=16 (R4-verified) ----
    s8v afr[8];
#pragma unroll
    for (int ti = 0; ti < 8; ++ti) {
        s8v a = {0, 0, 0, 0, 0, 0, 0, 0};
        if (g < 2) {
            const float* ap = A + (q * KK + TL[ti]) * CH + g * 8;
            f4 a0 = *(const f4*)ap;
            f4 a1 = *(const f4*)(ap + 4);
            a[0] = (short)bf16rne(a0.x); a[1] = (short)bf16rne(a0.y);
            a[2] = (short)bf16rne(a0.z); a[3] = (short)bf16rne(a0.w);
            a[4] = (short)bf16rne(a1.x); a[5] = (short)bf16rne(a1.y);
            a[6] = (short)bf16rne(a1.z); a[7] = (short)bf16rne(a1.w);
        } else if (g == 2) {
            a[0] = (short)bf16rne(b1[q * KK + TL[ti]]);
        }
        afr[ti] = a;
    }

    // ---- c2 = b2 + t_emb per tap as f4 over r (acc component layout) ----
    int xci[4];
    f4 c2q[8];
#pragma unroll
    for (int r = 0; r < 4; ++r) {
        const int l = 4 * g + r;
        xci[r] = (b * CH + l) * CST;
#pragma unroll
        for (int ti = 0; ti < 8; ++ti)
            c2q[ti][r] = b2[l * KK + TL[ti]] + tb[TL[ti]];
    }

    const int wc = w0 + q;
    const int wcol[3] = { (wc - 1) & (WW - 1), wc, (wc + 1) & (WW - 1) };

    const float* pvb = prev + (size_t)(b * CH + g * 8) * CST;   // deref'd only if g<2

    s8v bs_const = {0, 0, 0, 0, 0, 0, 0, 0};
    if (g == 2) bs_const[0] = (short)0x3F80;    // bf16 1.0 at k=16

    const float* xp0 = x + xci[0];
    const float* xp1 = x + xci[1];
    const float* xp2 = x + xci[2];
    const float* xp3 = x + xci[3];

    // ---- prev prefetch for j=0 ----
    float pp[8];
    if (g < 2) {
        const float* p0 = pvb + h0 * WW + wc;
#pragma unroll
        for (int e = 0; e < 8; ++e) pp[e] = p0[(size_t)e * CST];
    }

#pragma unroll 1
    for (int j = 0; j < 4; ++j) {
        const int h = h0 + j;
        const int sr[3] = { ((h - 1) & (HH - 1)) * WW, h * WW, ((h + 1) & (HH - 1)) * WW };

        // ---- B fragment from prefetched prev (issued a full row ago) ----
        s8v bs = bs_const;
        if (g < 2) {
#pragma unroll
            for (int e = 0; e < 8; ++e) bs[e] = (short)bf16rne(pp[e]);
        }
        // prefetch prev for next row (j=3 wraps to row h0: cached, harmless)
        if (g < 2) {
            const float* pn = pvb + (h0 + ((j + 1) & 3)) * WW + wc;
#pragma unroll
            for (int e = 0; e < 8; ++e) pp[e] = pn[(size_t)e * CST];
        }

        // ---- x preload for tap 0 (r-1, c-1) ----
        f4 xv, xn;
        {
            const int o0 = sr[0] + wcol[0];
            xv.x = xp0[o0]; xv.y = xp1[o0]; xv.z = xp2[o0]; xv.w = xp3[o0];
        }

        f4 o4 = splat4(0.0f);
#pragma unroll
        for (int ti = 0; ti < 8; ++ti) {
            f4 acc = {0.f, 0.f, 0.f, 0.f};
            acc = __builtin_amdgcn_mfma_f32_16x16x32_bf16(
                __builtin_bit_cast(b8v, afr[ti]), __builtin_bit_cast(b8v, bs), acc, 0, 0, 0);
            // distance-1 x prefetch: next tap's 4 channel taps issued under MFMA
            if (ti < 7) {
                const int tn = TL[ti + 1];
                const int o = sr[tn / 3] + wcol[tn % 3];
                xn.x = xp0[o]; xn.y = xp1[o]; xn.z = xp2[o]; xn.w = xp3[o];
            }
            // silu Taylor (s^4 dropped) + c2, conv MAC — packed fp32
            const f4 s2 = acc * acc;
            f4 kx = fma4(acc, splat4(0.5f), c2q[ti]);
            kx = fma4(s2, splat4(0.25f), kx);
            o4 = fma4(kx, xv, o4);
            xv = xn;
        }

        const int so = h * WW + wc;
        out[xci[0] + so] = o4.x;
        out[xci[1] + so] = o4.y;
        out[xci[2] + so] = o4.z;
        out[xci[3] + so] = o4.w;
    }
}

extern "C" void kernel_launch(void* const* d_in, const int* in_sizes, int n_in,
                              void* d_out, int out_size, void* d_ws, size_t ws_size,
                              hipStream_t stream)
{
    // 0:x 1:t 2:prev_output 3:A 4:b1 5:b2 6:W1 7:bm1 8:W2 9:bm2 10:W3 11:bm3
    const float* x    = (const float*)d_in[0];
    const float* t    = (const float*)d_in[1];
    const float* prev = (const float*)d_in[2];
    const float* A    = (const float*)d_in[3];
    const float* b1   = (const float*)d_in[4];
    const float* b2   = (const float*)d_in[5];
    const float* W1   = (const float*)d_in[6];
    const float* bm1  = (const float*)d_in[7];
    const float* W2   = (const float*)d_in[8];
    const float* bm2  = (const float*)d_in[9];
    const float* W3   = (const float*)d_in[10];
    const float* bm3  = (const float*)d_in[11];
    float* out = (float*)d_out;

    sdconv_mfma<<<BATCH * 256, 256, 0, stream>>>(
        x, prev, A, b1, b2, t, W1, bm1, W2, bm2, W3, bm3, out);
}